// Round 4
// baseline (648.544 us; speedup 1.0000x reference)
//
#include <hip/hip_runtime.h>
#include <stdint.h>

#define B_   8
#define S_   2048
#define D_   1024
#define E_   2048
#define SD_  128
#define M_   (B_ * S_)        // 16384
#define NUV  (2 * E_ + SD_)   // 4224

typedef __attribute__((ext_vector_type(8))) short short8;
typedef __attribute__((ext_vector_type(4))) float floatx4;

__device__ __forceinline__ ushort f2bf(float f) {
    uint32_t u = __float_as_uint(f);
    uint32_t r = (u + 0x7fffu + ((u >> 16) & 1u)) >> 16;  // RNE
    return (ushort)r;
}
__device__ __forceinline__ float bf2f(ushort h) {
    return __uint_as_float(((uint32_t)h) << 16);
}
__device__ __forceinline__ float silu(float z) {
    return z * __builtin_amdgcn_rcpf(1.0f + __expf(-z));
}

// serpentine band swizzle: 8 m-tiles per band, n fastest within band
__device__ __forceinline__ void tile_swizzle(int& mt, int& nt) {
    const int gx  = gridDim.x;
    const int lin = blockIdx.y * gx + blockIdx.x;
    const int band = lin / (gx * 8);
    const int r    = lin - band * gx * 8;
    mt = band * 8 + (r & 7);
    nt = r >> 3;
}

// ---------------------------------------------------------------------------
// Core: C[128x128] tile of A[M,K] @ B[N,K]^T, both K-contiguous bf16.
// 4 waves 2x2, wave tile 64x64 = 4x4 MFMA 16x16x32. BK=64, 32KB LDS.
// K-loop: register double-buffer (global_load_dwordx4 -> VGPR -> ds_write).
// Next tile's global loads issue right after the consume barrier; their
// latency is hidden by the MFMA phase, and barriers only drain lgkmcnt.
// LDS layout XOR-swizzled at 16B granularity (key=row&7): staging writes the
// permuted global chunk lane-linearly; fragment reads invert it -> 2-way
// bank aliasing (free) instead of 8-way.
// ---------------------------------------------------------------------------
__device__ __forceinline__ void gemm_core(
    const ushort* __restrict__ A, const ushort* __restrict__ B,
    int lda, int ldb, int K, int m0, int n0,
    ushort* ldsA, ushort* ldsB, floatx4 acc[4][4])
{
    const int t    = threadIdx.x;
    const int lane = t & 63;
    const int l15  = lane & 15;
    const int quad = lane >> 4;
    const int wave = t >> 6;
    const int wm   = (wave >> 1) * 64;
    const int wn   = (wave & 1) * 64;
    const int key  = l15 & 7;

    // staging: each tile 128x64 bf16 = 16KB = 1024 x 16B chunks; 4/thread/operand
    const ushort* gA[4]; const ushort* gB[4];
    ushort* lA[4]; ushort* lB[4];
    #pragma unroll
    for (int i = 0; i < 4; ++i) {
        const int c   = t + i * 256;
        const int row = c >> 3;
        const int gkc = ((c & 7) ^ (row & 7)) * 8;
        gA[i] = A + (size_t)(m0 + row) * lda + gkc;
        gB[i] = B + (size_t)(n0 + row) * ldb + gkc;
        lA[i] = ldsA + c * 8;
        lB[i] = ldsB + c * 8;
    }

    short8 rA[4], rB[4];
    #pragma unroll
    for (int i = 0; i < 4; ++i) rA[i] = *(const short8*)gA[i];
    #pragma unroll
    for (int i = 0; i < 4; ++i) rB[i] = *(const short8*)gB[i];

    for (int kk = 0; kk < K; kk += 64) {
        __syncthreads();  // all waves done reading LDS (prev iter)
        #pragma unroll
        for (int i = 0; i < 4; ++i) *(short8*)lA[i] = rA[i];
        #pragma unroll
        for (int i = 0; i < 4; ++i) *(short8*)lB[i] = rB[i];
        __syncthreads();  // ds_writes visible (lgkm drain only)

        if (kk + 64 < K) {  // issue next tile's loads; latency hidden by MFMAs
            #pragma unroll
            for (int i = 0; i < 4; ++i) rA[i] = *(const short8*)(gA[i] + kk + 64);
            #pragma unroll
            for (int i = 0; i < 4; ++i) rB[i] = *(const short8*)(gB[i] + kk + 64);
        }

        #pragma unroll
        for (int s = 0; s < 2; ++s) {
            const int koff = ((s * 4 + quad) ^ key) * 8;
            short8 af[4], bfr[4];
            #pragma unroll
            for (int mi = 0; mi < 4; ++mi)
                af[mi] = *(const short8*)(ldsA + (wm + mi * 16 + l15) * 64 + koff);
            #pragma unroll
            for (int ni = 0; ni < 4; ++ni)
                bfr[ni] = *(const short8*)(ldsB + (wn + ni * 16 + l15) * 64 + koff);
            #pragma unroll
            for (int mi = 0; mi < 4; ++mi)
                #pragma unroll
                for (int ni = 0; ni < 4; ++ni)
                    acc[mi][ni] = __builtin_amdgcn_mfma_f32_16x16x32_bf16(
                        af[mi], bfr[ni], acc[mi][ni], 0, 0, 0);
        }
    }
}

#define EPI_INDICES \
    const int t = threadIdx.x; \
    const int lane = t & 63, l15 = lane & 15, quad = lane >> 4; \
    const int wave = t >> 6, wm = (wave >> 1) * 64, wn = (wave & 1) * 64; \
    (void)t;

#define ZERO_ACC \
    floatx4 acc[4][4]; \
    _Pragma("unroll") \
    for (int i = 0; i < 4; ++i) \
        _Pragma("unroll") \
        for (int j = 0; j < 4; ++j) \
            _Pragma("unroll") \
            for (int r = 0; r < 4; ++r) acc[i][j][r] = 0.0f;

// ---------------------------------------------------------------------------
// prep kernels
// ---------------------------------------------------------------------------
__global__ __launch_bounds__(256) void k_cvt(const float* __restrict__ src,
                                             ushort* __restrict__ dst, int n4) {
    int i = blockIdx.x * 256 + threadIdx.x;
    if (i < n4) {
        float4 v = ((const float4*)src)[i];
        ushort4 o;
        o.x = f2bf(v.x); o.y = f2bf(v.y); o.z = f2bf(v.z); o.w = f2bf(v.w);
        ((ushort4*)dst)[i] = o;
    }
}

__global__ __launch_bounds__(256) void k_rmsnorm(const float* __restrict__ x,
                                                 const float* __restrict__ ln_g,
                                                 ushort* __restrict__ xnb) {
    const int m = blockIdx.x;
    const int t = threadIdx.x;
    float4 v = ((const float4*)(x + (size_t)m * D_))[t];
    float ss = v.x * v.x + v.y * v.y + v.z * v.z + v.w * v.w;
    #pragma unroll
    for (int off = 32; off > 0; off >>= 1) ss += __shfl_down(ss, off, 64);
    __shared__ float red[4];
    if ((t & 63) == 0) red[t >> 6] = ss;
    __syncthreads();
    float tot = red[0] + red[1] + red[2] + red[3];
    float rms = sqrtf(tot * (1.0f / (float)D_));
    float scale = ln_g[0] / fmaxf(rms, 1e-5f);
    ushort4 o;
    o.x = f2bf(v.x * scale); o.y = f2bf(v.y * scale);
    o.z = f2bf(v.z * scale); o.w = f2bf(v.w * scale);
    ((ushort4*)(xnb + (size_t)m * D_))[t] = o;
}

// ---------------------------------------------------------------------------
// GEMM1: uv = silu(xn @ uv_w^T); epilogue splits into u (row-major),
// vT (transposed via LDS, [B][E][S]), and q/k (affine + pos_enc).
// ---------------------------------------------------------------------------
__global__ __launch_bounds__(256) void k_gemm1(
    const ushort* __restrict__ xnb, const ushort* __restrict__ uvwb,
    const float* __restrict__ gamma, const float* __restrict__ beta,
    const float* __restrict__ pos,
    ushort* __restrict__ u, ushort* __restrict__ vT,
    ushort* __restrict__ qb, ushort* __restrict__ kb)
{
    __shared__ __align__(16) ushort lds[17408];  // 34KB: gemm 2x8192, transpose 128x136
    ushort* ldsA = lds;
    ushort* ldsB = lds + 8192;
    ZERO_ACC
    int mt, nt;
    tile_swizzle(mt, nt);
    const int m0 = mt * 128;
    const int n0 = nt * 128;
    gemm_core(xnb, uvwb, D_, D_, D_, m0, n0, ldsA, ldsB, acc);
    EPI_INDICES

    if (nt < 16) {           // u tiles, row-major bf16
        #pragma unroll
        for (int mi = 0; mi < 4; ++mi)
            #pragma unroll
            for (int ni = 0; ni < 4; ++ni) {
                const int col = n0 + wn + ni * 16 + l15;
                #pragma unroll
                for (int r = 0; r < 4; ++r) {
                    const int row = m0 + wm + mi * 16 + quad * 4 + r;
                    u[(size_t)row * E_ + col] = f2bf(silu(acc[mi][ni][r]));
                }
            }
    } else if (nt < 32) {    // v tiles -> write vT[b][e][s] via LDS transpose
        const int b   = m0 >> 11;            // m0 / S_  (tile within one batch)
        const int s0  = m0 & (S_ - 1);
        const int ec0 = n0 - E_;             // e base in [0,E)
        __syncthreads();  // all waves done with gemm LDS
        #pragma unroll
        for (int mi = 0; mi < 4; ++mi)
            #pragma unroll
            for (int ni = 0; ni < 4; ++ni) {
                const int col = wn + ni * 16 + l15;        // e-local
                const int row = wm + mi * 16 + quad * 4;   // s-local
                #pragma unroll
                for (int r = 0; r < 4; r += 2) {
                    ushort2 pr;
                    pr.x = f2bf(silu(acc[mi][ni][r]));
                    pr.y = f2bf(silu(acc[mi][ni][r + 1]));
                    *(ushort2*)&lds[col * 136 + row + r] = pr;
                }
            }
        __syncthreads();
        ushort* vTb = vT + ((size_t)b * E_ + ec0) * S_ + s0;
        #pragma unroll
        for (int i = 0; i < 8; ++i) {
            const int lin = i * 256 + t;
            const int e  = lin >> 4;
            const int sb = (lin & 15) * 8;
            *(short8*)(vTb + (size_t)e * S_ + sb) = *(const short8*)&lds[e * 136 + sb];
        }
    } else {                 // qk tile (exactly SDIM=128 cols)
        #pragma unroll
        for (int mi = 0; mi < 4; ++mi)
            #pragma unroll
            for (int ni = 0; ni < 4; ++ni) {
                const int sd = wn + ni * 16 + l15;  // 0..127
                const float g0 = gamma[sd], g1 = gamma[SD_ + sd];
                const float be0 = beta[sd], be1 = beta[SD_ + sd];
                #pragma unroll
                for (int r = 0; r < 4; ++r) {
                    const int row = m0 + wm + mi * 16 + quad * 4 + r;
                    const int srow = row & (S_ - 1);
                    float s = silu(acc[mi][ni][r]);
                    const float p = pos[(size_t)srow * SD_ + sd];
                    qb[(size_t)row * SD_ + sd] = f2bf(s * g0 + be0 + p);
                    kb[(size_t)row * SD_ + sd] = f2bf(s * g1 + be1 + p);
                }
            }
    }
}

// ---------------------------------------------------------------------------
// scores: kern = relu(q @ k^T / sqrt(SDIM))^2, bf16, batch group of 4
// ---------------------------------------------------------------------------
__global__ __launch_bounds__(256) void k_scores(
    const ushort* __restrict__ qb, const ushort* __restrict__ kb,
    ushort* __restrict__ kern, int b_off)
{
    __shared__ __align__(16) ushort ldsA[128 * 64];
    __shared__ __align__(16) ushort ldsB[128 * 64];
    ZERO_ACC
    const int bz = blockIdx.z;
    const int b  = b_off + bz;
    int mt, nt;
    tile_swizzle(mt, nt);
    const int m0 = mt * 128;
    const int n0 = nt * 128;
    gemm_core(qb + (size_t)b * S_ * SD_, kb + (size_t)b * S_ * SD_,
              SD_, SD_, SD_, m0, n0, ldsA, ldsB, acc);
    EPI_INDICES
    ushort* ko = kern + (size_t)bz * S_ * S_;
    const float inv = 0.08838834764831845f;  // 1/sqrt(128)
    #pragma unroll
    for (int mi = 0; mi < 4; ++mi)
        #pragma unroll
        for (int ni = 0; ni < 4; ++ni) {
            const int col = n0 + wn + ni * 16 + l15;
            #pragma unroll
            for (int r = 0; r < 4; ++r) {
                const int row = m0 + wm + mi * 16 + quad * 4 + r;
                float s = fmaxf(acc[mi][ni][r] * inv, 0.0f);
                ko[(size_t)row * S_ + col] = f2bf(s * s);
            }
        }
}

// ---------------------------------------------------------------------------
// kv: kvu = u .* (kern @ v), bf16, batch group of 4
// ---------------------------------------------------------------------------
__global__ __launch_bounds__(256) void k_kv(
    const ushort* __restrict__ kern, const ushort* __restrict__ vT,
    const ushort* __restrict__ u, ushort* __restrict__ kvu, int b_off)
{
    __shared__ __align__(16) ushort ldsA[128 * 64];
    __shared__ __align__(16) ushort ldsB[128 * 64];
    ZERO_ACC
    const int bz = blockIdx.z;
    const int b  = b_off + bz;
    int mt, nt;
    tile_swizzle(mt, nt);
    const int m0 = mt * 128;
    const int n0 = nt * 128;
    gemm_core(kern + (size_t)bz * S_ * S_, vT + (size_t)b * E_ * S_,
              S_, S_, S_, m0, n0, ldsA, ldsB, acc);
    EPI_INDICES
    #pragma unroll
    for (int mi = 0; mi < 4; ++mi)
        #pragma unroll
        for (int ni = 0; ni < 4; ++ni) {
            const int col = n0 + wn + ni * 16 + l15;
            #pragma unroll
            for (int r = 0; r < 4; ++r) {
                const int row = m0 + wm + mi * 16 + quad * 4 + r;
                const size_t gi = (size_t)(b * S_ + row) * E_ + col;
                float uval = bf2f(u[gi]);
                kvu[gi] = f2bf(uval * acc[mi][ni][r]);
            }
        }
}

// ---------------------------------------------------------------------------
// out: out = x * res_scale + kvu @ o_w^T  (fp32 out)
// ---------------------------------------------------------------------------
__global__ __launch_bounds__(256) void k_out(
    const ushort* __restrict__ kvu, const ushort* __restrict__ owb,
    const float* __restrict__ x, const float* __restrict__ res_scale,
    float* __restrict__ out)
{
    __shared__ __align__(16) ushort ldsA[128 * 64];
    __shared__ __align__(16) ushort ldsB[128 * 64];
    ZERO_ACC
    int mt, nt;
    tile_swizzle(mt, nt);
    const int m0 = mt * 128;
    const int n0 = nt * 128;
    gemm_core(kvu, owb, E_, E_, E_, m0, n0, ldsA, ldsB, acc);
    EPI_INDICES
    #pragma unroll
    for (int mi = 0; mi < 4; ++mi)
        #pragma unroll
        for (int ni = 0; ni < 4; ++ni) {
            const int col = n0 + wn + ni * 16 + l15;
            const float rs = res_scale[col];
            #pragma unroll
            for (int r = 0; r < 4; ++r) {
                const int row = m0 + wm + mi * 16 + quad * 4 + r;
                const size_t gi = (size_t)row * D_ + col;
                out[gi] = x[gi] * rs + acc[mi][ni][r];
            }
        }
}

// ---------------------------------------------------------------------------
// Workspace layout (~235 MiB total):
//   region0 33.55MB : xnb (rmsnorm->gemm1), then kern chunk (4 batches)
//   uvwb 8.65MB | owb 4.19MB | u 67.11MB | kvu 67.11MB | vT 67.11MB
//   qb 4.19MB | kb 4.19MB
// ---------------------------------------------------------------------------
extern "C" void kernel_launch(void* const* d_in, const int* in_sizes, int n_in,
                              void* d_out, int out_size, void* d_ws, size_t ws_size,
                              hipStream_t stream)
{
    const float* x         = (const float*)d_in[0];
    const float* pos       = (const float*)d_in[1];
    const float* ln_g      = (const float*)d_in[2];
    const float* uv_w      = (const float*)d_in[3];
    const float* gamma     = (const float*)d_in[4];
    const float* beta      = (const float*)d_in[5];
    const float* o_w       = (const float*)d_in[6];
    const float* res_scale = (const float*)d_in[7];
    float* out = (float*)d_out;

    char* p = (char*)d_ws;
    ushort* region0 = (ushort*)p; p += (size_t)M_ * D_ * 2;
    ushort* uvwb    = (ushort*)p; p += (size_t)NUV * D_ * 2;
    ushort* owb     = (ushort*)p; p += (size_t)D_ * E_ * 2;
    ushort* u       = (ushort*)p; p += (size_t)M_ * E_ * 2;
    ushort* kvu     = (ushort*)p; p += (size_t)M_ * E_ * 2;
    ushort* vT      = (ushort*)p; p += (size_t)M_ * E_ * 2;
    ushort* qb      = (ushort*)p; p += (size_t)M_ * SD_ * 2;
    ushort* kb      = (ushort*)p; p += (size_t)M_ * SD_ * 2;

    ushort* xnb  = region0;   // dead after k_gemm1
    ushort* kern = region0;   // 4-batch chunk

    k_cvt<<<(NUV * D_ / 4 + 255) / 256, 256, 0, stream>>>(uv_w, uvwb, NUV * D_ / 4);
    k_cvt<<<(D_ * E_ / 4 + 255) / 256, 256, 0, stream>>>(o_w, owb, D_ * E_ / 4);
    k_rmsnorm<<<M_, 256, 0, stream>>>(x, ln_g, xnb);
    k_gemm1<<<dim3(NUV / 128, M_ / 128), 256, 0, stream>>>(xnb, uvwb, gamma, beta, pos, u, vT, qb, kb);
    for (int g = 0; g < 2; ++g) {
        k_scores<<<dim3(S_ / 128, S_ / 128, 4), 256, 0, stream>>>(qb, kb, kern, g * 4);
        k_kv<<<dim3(E_ / 128, S_ / 128, 4), 256, 0, stream>>>(kern, vT, u, kvu, g * 4);
    }
    k_out<<<dim3(D_ / 128, M_ / 128), 256, 0, stream>>>(kvu, owb, x, res_scale, out);
}

// Round 5
// 579.992 us; speedup vs baseline: 1.1182x; 1.1182x over previous
//
#include <hip/hip_runtime.h>
#include <stdint.h>

#define B_   8
#define S_   2048
#define D_   1024
#define E_   2048
#define SD_  128
#define M_   (B_ * S_)        // 16384
#define NUV  (2 * E_ + SD_)   // 4224

typedef __attribute__((ext_vector_type(8))) short short8;
typedef __attribute__((ext_vector_type(4))) float floatx4;

typedef __attribute__((address_space(1))) void as1_void;
typedef __attribute__((address_space(3))) void as3_void;

__device__ __forceinline__ ushort f2bf(float f) {
    uint32_t u = __float_as_uint(f);
    uint32_t r = (u + 0x7fffu + ((u >> 16) & 1u)) >> 16;  // RNE
    return (ushort)r;
}
__device__ __forceinline__ float bf2f(ushort h) {
    return __uint_as_float(((uint32_t)h) << 16);
}
__device__ __forceinline__ float silu(float z) {
    return z * __builtin_amdgcn_rcpf(1.0f + __expf(-z));
}

__device__ __forceinline__ void gld_lds16(const ushort* g, ushort* l) {
    __builtin_amdgcn_global_load_lds((const as1_void*)g, (as3_void*)l, 16, 0, 0);
}

// Two-level supertile swizzle: 8 m-tiles x 4 n-tiles per supertile (32 blocks).
// Working set/supertile = 2MB A-band + 1MB B-chunk -> fits one XCD L2; with
// round-robin XCD dispatch, XCD i gets (m_local==i, all 4 n) = ~1.25MB hot set.
__device__ __forceinline__ void tile_swizzle(int& mt, int& nt) {
    const int gx  = gridDim.x;                 // n-tiles
    const int lin = blockIdx.y * gx + blockIdx.x;
    const int bandSz = gx * 8;
    const int band = lin / bandSz;
    const int rem  = lin - band * bandSz;
    const int full = gx >> 2;                  // # full 4-wide n-chunks
    const int sc   = rem >> 5;                 // /32
    if (sc < full) {
        const int r2 = rem & 31;
        mt = band * 8 + (r2 & 7);
        nt = sc * 4 + (r2 >> 3);
    } else {                                   // remainder chunk (gx%4 cols)
        const int r3 = rem - full * 32;
        mt = band * 8 + (r3 & 7);
        nt = full * 4 + (r3 >> 3);
    }
}

// ---------------------------------------------------------------------------
// Core: C[128x128] tile of A[M,K] @ B[N,K]^T, both K-contiguous bf16.
// 4 waves 2x2, wave tile 64x64 = 4x4 MFMA 16x16x32. BK=64, 32KB LDS.
// R3 structure: global_load_lds width=16, 2-barrier K-loop (proven 656 TF).
// LDS XOR-swizzled at 16B granularity (key=row&7) -> 0 bank conflicts.
// ---------------------------------------------------------------------------
__device__ __forceinline__ void gemm_core(
    const ushort* __restrict__ A, const ushort* __restrict__ B,
    int lda, int ldb, int K, int m0, int n0,
    ushort* ldsA, ushort* ldsB, floatx4 acc[4][4])
{
    const int t    = threadIdx.x;
    const int lane = t & 63;
    const int l15  = lane & 15;
    const int quad = lane >> 4;
    const int wave = t >> 6;
    const int wm   = (wave >> 1) * 64;
    const int wn   = (wave & 1) * 64;
    const int key  = l15 & 7;

    // staging: each tile 128x64 bf16 = 16KB = 1024 x 16B chunks; 4/thread/operand
    const ushort* gA[4]; const ushort* gB[4];
    ushort* lA[4]; ushort* lB[4];
    #pragma unroll
    for (int i = 0; i < 4; ++i) {
        const int c   = t + i * 256;
        const int row = c >> 3;
        const int gkc = ((c & 7) ^ (row & 7)) * 8;
        gA[i] = A + (size_t)(m0 + row) * lda + gkc;
        gB[i] = B + (size_t)(n0 + row) * ldb + gkc;
        lA[i] = ldsA + c * 8;
        lB[i] = ldsB + c * 8;
    }

    for (int kk = 0; kk < K; kk += 64) {
        __syncthreads();
        #pragma unroll
        for (int i = 0; i < 4; ++i) gld_lds16(gA[i] + kk, lA[i]);
        #pragma unroll
        for (int i = 0; i < 4; ++i) gld_lds16(gB[i] + kk, lB[i]);
        __syncthreads();  // vmcnt(0) drain -> staged data visible

        #pragma unroll
        for (int s = 0; s < 2; ++s) {
            const int koff = ((s * 4 + quad) ^ key) * 8;
            short8 af[4], bfr[4];
            #pragma unroll
            for (int mi = 0; mi < 4; ++mi)
                af[mi] = *(const short8*)(ldsA + (wm + mi * 16 + l15) * 64 + koff);
            #pragma unroll
            for (int ni = 0; ni < 4; ++ni)
                bfr[ni] = *(const short8*)(ldsB + (wn + ni * 16 + l15) * 64 + koff);
            #pragma unroll
            for (int mi = 0; mi < 4; ++mi)
                #pragma unroll
                for (int ni = 0; ni < 4; ++ni)
                    acc[mi][ni] = __builtin_amdgcn_mfma_f32_16x16x32_bf16(
                        af[mi], bfr[ni], acc[mi][ni], 0, 0, 0);
        }
    }
}

#define EPI_INDICES \
    const int t = threadIdx.x; \
    const int lane = t & 63, l15 = lane & 15, quad = lane >> 4; \
    const int wave = t >> 6, wm = (wave >> 1) * 64, wn = (wave & 1) * 64; \
    (void)t;

#define ZERO_ACC \
    floatx4 acc[4][4]; \
    _Pragma("unroll") \
    for (int i = 0; i < 4; ++i) \
        _Pragma("unroll") \
        for (int j = 0; j < 4; ++j) \
            _Pragma("unroll") \
            for (int r = 0; r < 4; ++r) acc[i][j][r] = 0.0f;

// ---------------------------------------------------------------------------
// prep kernels
// ---------------------------------------------------------------------------
__global__ __launch_bounds__(256) void k_cvt(const float* __restrict__ src,
                                             ushort* __restrict__ dst, int n4) {
    int i = blockIdx.x * 256 + threadIdx.x;
    if (i < n4) {
        float4 v = ((const float4*)src)[i];
        ushort4 o;
        o.x = f2bf(v.x); o.y = f2bf(v.y); o.z = f2bf(v.z); o.w = f2bf(v.w);
        ((ushort4*)dst)[i] = o;
    }
}

__global__ __launch_bounds__(256) void k_rmsnorm(const float* __restrict__ x,
                                                 const float* __restrict__ ln_g,
                                                 ushort* __restrict__ xnb) {
    const int m = blockIdx.x;
    const int t = threadIdx.x;
    float4 v = ((const float4*)(x + (size_t)m * D_))[t];
    float ss = v.x * v.x + v.y * v.y + v.z * v.z + v.w * v.w;
    #pragma unroll
    for (int off = 32; off > 0; off >>= 1) ss += __shfl_down(ss, off, 64);
    __shared__ float red[4];
    if ((t & 63) == 0) red[t >> 6] = ss;
    __syncthreads();
    float tot = red[0] + red[1] + red[2] + red[3];
    float rms = sqrtf(tot * (1.0f / (float)D_));
    float scale = ln_g[0] / fmaxf(rms, 1e-5f);
    ushort4 o;
    o.x = f2bf(v.x * scale); o.y = f2bf(v.y * scale);
    o.z = f2bf(v.z * scale); o.w = f2bf(v.w * scale);
    ((ushort4*)(xnb + (size_t)m * D_))[t] = o;
}

// ---------------------------------------------------------------------------
// GEMM1: uv = silu(xn @ uv_w^T); epilogue splits into u (row-major),
// vT (transposed via LDS, [B][E][S]), and q/k (affine + pos_enc).
// ---------------------------------------------------------------------------
__global__ __launch_bounds__(256, 3) void k_gemm1(
    const ushort* __restrict__ xnb, const ushort* __restrict__ uvwb,
    const float* __restrict__ gamma, const float* __restrict__ beta,
    const float* __restrict__ pos,
    ushort* __restrict__ u, ushort* __restrict__ vT,
    ushort* __restrict__ qb, ushort* __restrict__ kb)
{
    __shared__ __align__(16) ushort lds[17408];  // 34KB: gemm 2x8192, transpose 128x136
    ushort* ldsA = lds;
    ushort* ldsB = lds + 8192;
    ZERO_ACC
    int mt, nt;
    tile_swizzle(mt, nt);
    const int m0 = mt * 128;
    const int n0 = nt * 128;
    gemm_core(xnb, uvwb, D_, D_, D_, m0, n0, ldsA, ldsB, acc);
    EPI_INDICES

    if (nt < 16) {           // u tiles, row-major bf16
        #pragma unroll
        for (int mi = 0; mi < 4; ++mi)
            #pragma unroll
            for (int ni = 0; ni < 4; ++ni) {
                const int col = n0 + wn + ni * 16 + l15;
                #pragma unroll
                for (int r = 0; r < 4; ++r) {
                    const int row = m0 + wm + mi * 16 + quad * 4 + r;
                    u[(size_t)row * E_ + col] = f2bf(silu(acc[mi][ni][r]));
                }
            }
    } else if (nt < 32) {    // v tiles -> write vT[b][e][s] via LDS transpose
        const int b   = m0 >> 11;            // m0 / S_
        const int s0  = m0 & (S_ - 1);
        const int ec0 = n0 - E_;             // e base in [0,E)
        __syncthreads();  // all waves done with gemm LDS
        #pragma unroll
        for (int mi = 0; mi < 4; ++mi)
            #pragma unroll
            for (int ni = 0; ni < 4; ++ni) {
                const int col = wn + ni * 16 + l15;        // e-local
                const int row = wm + mi * 16 + quad * 4;   // s-local
                #pragma unroll
                for (int r = 0; r < 4; r += 2) {
                    ushort2 pr;
                    pr.x = f2bf(silu(acc[mi][ni][r]));
                    pr.y = f2bf(silu(acc[mi][ni][r + 1]));
                    *(ushort2*)&lds[col * 136 + row + r] = pr;
                }
            }
        __syncthreads();
        ushort* vTb = vT + ((size_t)b * E_ + ec0) * S_ + s0;
        #pragma unroll
        for (int i = 0; i < 8; ++i) {
            const int lin = i * 256 + t;
            const int e  = lin >> 4;
            const int sb = (lin & 15) * 8;
            *(short8*)(vTb + (size_t)e * S_ + sb) = *(const short8*)&lds[e * 136 + sb];
        }
    } else {                 // qk tile (exactly SDIM=128 cols)
        #pragma unroll
        for (int mi = 0; mi < 4; ++mi)
            #pragma unroll
            for (int ni = 0; ni < 4; ++ni) {
                const int sd = wn + ni * 16 + l15;  // 0..127
                const float g0 = gamma[sd], g1 = gamma[SD_ + sd];
                const float be0 = beta[sd], be1 = beta[SD_ + sd];
                #pragma unroll
                for (int r = 0; r < 4; ++r) {
                    const int row = m0 + wm + mi * 16 + quad * 4 + r;
                    const int srow = row & (S_ - 1);
                    float s = silu(acc[mi][ni][r]);
                    const float p = pos[(size_t)srow * SD_ + sd];
                    qb[(size_t)row * SD_ + sd] = f2bf(s * g0 + be0 + p);
                    kb[(size_t)row * SD_ + sd] = f2bf(s * g1 + be1 + p);
                }
            }
    }
}

// ---------------------------------------------------------------------------
// scores: kern = relu(q @ k^T / sqrt(SDIM))^2, bf16, batch group of 4
// ---------------------------------------------------------------------------
__global__ __launch_bounds__(256, 3) void k_scores(
    const ushort* __restrict__ qb, const ushort* __restrict__ kb,
    ushort* __restrict__ kern, int b_off)
{
    __shared__ __align__(16) ushort ldsA[128 * 64];
    __shared__ __align__(16) ushort ldsB[128 * 64];
    ZERO_ACC
    const int bz = blockIdx.z;
    const int b  = b_off + bz;
    int mt, nt;
    tile_swizzle(mt, nt);
    const int m0 = mt * 128;
    const int n0 = nt * 128;
    gemm_core(qb + (size_t)b * S_ * SD_, kb + (size_t)b * S_ * SD_,
              SD_, SD_, SD_, m0, n0, ldsA, ldsB, acc);
    EPI_INDICES
    ushort* ko = kern + (size_t)bz * S_ * S_;
    const float inv = 0.08838834764831845f;  // 1/sqrt(128)
    #pragma unroll
    for (int mi = 0; mi < 4; ++mi)
        #pragma unroll
        for (int ni = 0; ni < 4; ++ni) {
            const int col = n0 + wn + ni * 16 + l15;
            #pragma unroll
            for (int r = 0; r < 4; ++r) {
                const int row = m0 + wm + mi * 16 + quad * 4 + r;
                float s = fmaxf(acc[mi][ni][r] * inv, 0.0f);
                ko[(size_t)row * S_ + col] = f2bf(s * s);
            }
        }
}

// ---------------------------------------------------------------------------
// kv: kvu = u .* (kern @ v), bf16, batch group of 4
// ---------------------------------------------------------------------------
__global__ __launch_bounds__(256, 3) void k_kv(
    const ushort* __restrict__ kern, const ushort* __restrict__ vT,
    const ushort* __restrict__ u, ushort* __restrict__ kvu, int b_off)
{
    __shared__ __align__(16) ushort ldsA[128 * 64];
    __shared__ __align__(16) ushort ldsB[128 * 64];
    ZERO_ACC
    const int bz = blockIdx.z;
    const int b  = b_off + bz;
    int mt, nt;
    tile_swizzle(mt, nt);
    const int m0 = mt * 128;
    const int n0 = nt * 128;
    gemm_core(kern + (size_t)bz * S_ * S_, vT + (size_t)b * E_ * S_,
              S_, S_, S_, m0, n0, ldsA, ldsB, acc);
    EPI_INDICES
    #pragma unroll
    for (int mi = 0; mi < 4; ++mi)
        #pragma unroll
        for (int ni = 0; ni < 4; ++ni) {
            const int col = n0 + wn + ni * 16 + l15;
            #pragma unroll
            for (int r = 0; r < 4; ++r) {
                const int row = m0 + wm + mi * 16 + quad * 4 + r;
                const size_t gi = (size_t)(b * S_ + row) * E_ + col;
                float uval = bf2f(u[gi]);
                kvu[gi] = f2bf(uval * acc[mi][ni][r]);
            }
        }
}

// ---------------------------------------------------------------------------
// out: out = x * res_scale + kvu @ o_w^T  (fp32 out)
// ---------------------------------------------------------------------------
__global__ __launch_bounds__(256, 3) void k_out(
    const ushort* __restrict__ kvu, const ushort* __restrict__ owb,
    const float* __restrict__ x, const float* __restrict__ res_scale,
    float* __restrict__ out)
{
    __shared__ __align__(16) ushort ldsA[128 * 64];
    __shared__ __align__(16) ushort ldsB[128 * 64];
    ZERO_ACC
    int mt, nt;
    tile_swizzle(mt, nt);
    const int m0 = mt * 128;
    const int n0 = nt * 128;
    gemm_core(kvu, owb, E_, E_, E_, m0, n0, ldsA, ldsB, acc);
    EPI_INDICES
    #pragma unroll
    for (int mi = 0; mi < 4; ++mi)
        #pragma unroll
        for (int ni = 0; ni < 4; ++ni) {
            const int col = n0 + wn + ni * 16 + l15;
            const float rs = res_scale[col];
            #pragma unroll
            for (int r = 0; r < 4; ++r) {
                const int row = m0 + wm + mi * 16 + quad * 4 + r;
                const size_t gi = (size_t)row * D_ + col;
                out[gi] = x[gi] * rs + acc[mi][ni][r];
            }
        }
}

// ---------------------------------------------------------------------------
// Workspace layout (~235 MiB total):
//   region0 33.55MB : xnb (rmsnorm->gemm1), then kern chunk (4 batches)
//   uvwb 8.65MB | owb 4.19MB | u 67.11MB | kvu 67.11MB | vT 67.11MB
//   qb 4.19MB | kb 4.19MB
// ---------------------------------------------------------------------------
extern "C" void kernel_launch(void* const* d_in, const int* in_sizes, int n_in,
                              void* d_out, int out_size, void* d_ws, size_t ws_size,
                              hipStream_t stream)
{
    const float* x         = (const float*)d_in[0];
    const float* pos       = (const float*)d_in[1];
    const float* ln_g      = (const float*)d_in[2];
    const float* uv_w      = (const float*)d_in[3];
    const float* gamma     = (const float*)d_in[4];
    const float* beta      = (const float*)d_in[5];
    const float* o_w       = (const float*)d_in[6];
    const float* res_scale = (const float*)d_in[7];
    float* out = (float*)d_out;

    char* p = (char*)d_ws;
    ushort* region0 = (ushort*)p; p += (size_t)M_ * D_ * 2;
    ushort* uvwb    = (ushort*)p; p += (size_t)NUV * D_ * 2;
    ushort* owb     = (ushort*)p; p += (size_t)D_ * E_ * 2;
    ushort* u       = (ushort*)p; p += (size_t)M_ * E_ * 2;
    ushort* kvu     = (ushort*)p; p += (size_t)M_ * E_ * 2;
    ushort* vT      = (ushort*)p; p += (size_t)M_ * E_ * 2;
    ushort* qb      = (ushort*)p; p += (size_t)M_ * SD_ * 2;
    ushort* kb      = (ushort*)p; p += (size_t)M_ * SD_ * 2;

    ushort* xnb  = region0;   // dead after k_gemm1
    ushort* kern = region0;   // 4-batch chunk

    k_cvt<<<(NUV * D_ / 4 + 255) / 256, 256, 0, stream>>>(uv_w, uvwb, NUV * D_ / 4);
    k_cvt<<<(D_ * E_ / 4 + 255) / 256, 256, 0, stream>>>(o_w, owb, D_ * E_ / 4);
    k_rmsnorm<<<M_, 256, 0, stream>>>(x, ln_g, xnb);
    k_gemm1<<<dim3(NUV / 128, M_ / 128), 256, 0, stream>>>(xnb, uvwb, gamma, beta, pos, u, vT, qb, kb);
    for (int g = 0; g < 2; ++g) {
        k_scores<<<dim3(S_ / 128, S_ / 128, 4), 256, 0, stream>>>(qb, kb, kern, g * 4);
        k_kv<<<dim3(E_ / 128, S_ / 128, 4), 256, 0, stream>>>(kern, vT, u, kvu, g * 4);
    }
    k_out<<<dim3(D_ / 128, M_ / 128), 256, 0, stream>>>(kvu, owb, x, res_scale, out);
}